// Round 5
// baseline (1363.365 us; speedup 1.0000x reference)
//
#include <hip/hip_runtime.h>

// Problem constants
#define BB   4
#define CIN  64
#define HH   256
#define WW   256
#define QQ   256
#define KK   16

typedef _Float16 half8 __attribute__((ext_vector_type(8)));
typedef float   f32x16 __attribute__((ext_vector_type(16)));

// ---- workspace layout (bytes) ----
#define OFF_W1R   0ull
#define OFF_W2R   294912ull
#define OFF_WMU   1474560ull
#define OFF_LGB   1490944ull
#define OFF_BUF1  1605888ull
#define OFF_BUF2  35160320ull
// total needed: 68714752 bytes (~65.5 MiB)

// ---------------------------------------------------------------------------
// Prep: reorder conv weights OIHW -> [o][tap][c] fp16; fold head:
// wmu2[k][c] = 2 * sum_o mu[k][o]*w3[o][c];  lgb[k] = 2*mu_k.b3 - |mu_k|^2
// ---------------------------------------------------------------------------
__global__ __launch_bounds__(256) void k_prep(
    const float* __restrict__ w1, const float* __restrict__ w2,
    const float* __restrict__ w3, const float* __restrict__ b3,
    const float* __restrict__ mu,
    _Float16* __restrict__ w1r, _Float16* __restrict__ w2r,
    float* __restrict__ wmu2, float* __restrict__ lgb) {
  int idx = blockIdx.x * 256 + threadIdx.x;
  if (idx < 147456) {                       // w1r: [256 o][9 t][64 c]
    int o = idx / 576, rem = idx - o * 576;
    int t = rem >> 6, c = rem & 63;
    w1r[idx] = (_Float16)w1[(o * 64 + c) * 9 + t];
  } else if (idx < 737280) {                // w2r: [256 o][9 t][256 c]
    int j = idx - 147456;
    int o = j / 2304, rem = j - o * 2304;
    int t = rem >> 8, c = rem & 255;
    w2r[j] = (_Float16)w2[(o * 256 + c) * 9 + t];
  } else if (idx < 741376) {                // wmu2: [16 k][256 c]
    int j = idx - 737280;
    int k = j >> 8, c = j & 255;
    float s = 0.f;
    for (int o = 0; o < 256; ++o) s = fmaf(mu[k * 256 + o], w3[o * 256 + c], s);
    wmu2[j] = 2.f * s;
  } else if (idx < 741392) {                // lgb: [16]
    int k = idx - 741376;
    float s1 = 0.f, s2 = 0.f;
    for (int o = 0; o < 256; ++o) {
      float m = mu[k * 256 + o];
      s1 = fmaf(m, b3[o], s1);
      s2 = fmaf(m, m, s2);
    }
    lgb[k] = 2.f * s1 - s2;
  }
}

// ---------------------------------------------------------------------------
// T0: one batch of x NCHW fp32 -> act0 [HW][64] fp16 (LDS transpose)
// ---------------------------------------------------------------------------
__global__ __launch_bounds__(256) void k_t0(const float* __restrict__ x,
                                            _Float16* __restrict__ act0) {
  __shared__ float tile[64][65];
  int p0 = blockIdx.x << 6;
  int t = threadIdx.x;
  {
    int p = t & 63, c0 = t >> 6;
    const float* xb = x + p0 + p;
#pragma unroll
    for (int i = 0; i < 16; ++i) {
      int c = c0 + (i << 2);
      tile[c][p] = xb[(size_t)c * 65536];
    }
  }
  __syncthreads();
  {
    int c = t & 63, p1 = t >> 6;
    _Float16* o = act0 + (size_t)p0 * CIN + c;
#pragma unroll
    for (int i = 0; i < 16; ++i) {
      int p = p1 + (i << 2);
      o[(size_t)p * CIN] = (_Float16)tile[c][p];
    }
  }
}

// ---------------------------------------------------------------------------
// Conv 3x3 (replicate pad) + bias + ReLU, implicit GEMM, 32x32x16 fp16 MFMA.
// Block: 256 thr (4 waves, 2x2), tile 128 px (16w x 8h) x 256 ch (full N).
// Wave tile: 64 px x 128 ch = 2 M-subtiles x 4 N-tiles of 32x32 (acc 128
// VGPR). Bytes/MAC = 0.047 (was 0.0625) -> LDS read pipe no longer binding.
// Bs double-buffered, B reg-prefetched 2 taps deep, 1 barrier/tap.
// grid 512 = txi(4b) | tyi(5b); 2 blocks/CU co-resident.
// ---------------------------------------------------------------------------
template <int CI>
__global__ __launch_bounds__(256, 2) void k_conv(
    const _Float16* __restrict__ actin, const _Float16* __restrict__ wr,
    const float* __restrict__ bias, _Float16* __restrict__ actout) {
  constexpr int KROW = 9 * CI;
  constexpr int NC = CI / 32;
  constexpr int NT = 9 * NC;
  __shared__ __align__(16) _Float16 As[180 * 40];     // 14400 B
  __shared__ __align__(16) _Float16 Bs[2][256 * 40];  // 2 x 20480 B

  int tid = threadIdx.x;
  int txi = blockIdx.x & 15, tyi = blockIdx.x >> 4;
  int x0 = txi << 4, y0 = tyi << 3;
  int lane = tid & 63, wave = tid >> 6;
  int mwave = wave >> 1, nwave = wave & 1;
  int l31 = lane & 31, khalf = lane >> 5;

  f32x16 acc[2][4];
#pragma unroll
  for (int s = 0; s < 2; ++s)
#pragma unroll
    for (int nt = 0; nt < 4; ++nt)
#pragma unroll
      for (int r = 0; r < 16; ++r) acc[s][nt][r] = 0.f;

  bool doA = tid < 180;
  const _Float16* asrc = actin;
  if (doA) {
    int hy = tid / 18, hx = tid - hy * 18;
    int y = min(max(y0 - 1 + hy, 0), 255);
    int x = min(max(x0 - 1 + hx, 0), 255);
    asrc = actin + ((size_t)(y * 256 + x)) * CI;
  }

  // B staging: thread covers rows brow, brow+64, brow+128, brow+192
  int brow = tid >> 2, bq = tid & 3;
  const _Float16* bsrc = wr + (size_t)brow * KROW + bq * 8;

  uint4 s0[4], s1[4], ar[4];

  auto ldB = [&](int tt, int ccx, uint4* p) {
    int off = tt * CI + (ccx << 5);
    p[0] = *(const uint4*)(bsrc + off);
    p[1] = *(const uint4*)(bsrc + (size_t)64 * KROW + off);
    p[2] = *(const uint4*)(bsrc + (size_t)128 * KROW + off);
    p[3] = *(const uint4*)(bsrc + (size_t)192 * KROW + off);
  };
  auto stB = [&](int sb, uint4* p) {
    ((uint4*)&Bs[sb][brow * 40])[bq] = p[0];
    ((uint4*)&Bs[sb][(brow + 64) * 40])[bq] = p[1];
    ((uint4*)&Bs[sb][(brow + 128) * 40])[bq] = p[2];
    ((uint4*)&Bs[sb][(brow + 192) * 40])[bq] = p[3];
  };
  auto ldA = [&](int ccx) {
    const uint4* sp = (const uint4*)(asrc + (ccx << 5));
    ar[0] = sp[0]; ar[1] = sp[1]; ar[2] = sp[2]; ar[3] = sp[3];
  };
  auto stA = [&]() {
    uint4* d = (uint4*)&As[tid * 40];
    d[0] = ar[0]; d[1] = ar[1]; d[2] = ar[2]; d[3] = ar[3];
  };

  // Prologue: stage B(0), A(0); prefetch B(1),B(2), A(1) into registers.
  ldB(0, 0, s0);
  if (doA) ldA(0);
  stB(0, s0);
  if (doA) stA();
  ldB(1, 0, s0);                 // regs s0 <- B(1)
  ldB(2, 0, s1);                 // regs s1 <- B(2)   (NT >= 9 always)
  if (doA) ldA(NC > 1 ? 1 : 0);
  __syncthreads();

  for (int cc = 0; cc < NC; ++cc) {
#pragma unroll
    for (int t = 0; t < 9; ++t) {
      int j = cc * 9 + t;
      int sb = j & 1;
      int dy = t / 3, dx = t - dy * 3;
      half8 af[2][2], bf[2][4];
#pragma unroll
      for (int ks = 0; ks < 2; ++ks) {
#pragma unroll
        for (int s = 0; s < 2; ++s) {
          int pix = (mwave * 4 + s * 2 + (l31 >> 4) + dy) * 18 + (l31 & 15) + dx;
          af[ks][s] = *(const half8*)&As[pix * 40 + ks * 16 + khalf * 8];
        }
#pragma unroll
        for (int nt = 0; nt < 4; ++nt)
          bf[ks][nt] = *(const half8*)&Bs[sb][(nwave * 128 + nt * 32 + l31) * 40 +
                                             ks * 16 + khalf * 8];
      }
      if (j + 1 < NT) {
        // stage next tap's B (regs -> other LDS buffer), prefetch tap j+3
        int jn_t, jn_c;
        if (j + 3 < NT) { jn_t = (t >= 6) ? t - 6 : t + 3; jn_c = cc + (t >= 6); }
        else            { jn_t = 8; jn_c = NC - 1; }
        if (sb == 0) { stB(1, s0); ldB(jn_t, jn_c, s0); }
        else         { stB(0, s1); ldB(jn_t, jn_c, s1); }
      }
#pragma unroll
      for (int ks = 0; ks < 2; ++ks)
#pragma unroll
        for (int s = 0; s < 2; ++s)
#pragma unroll
          for (int nt = 0; nt < 4; ++nt)
            acc[s][nt] = __builtin_amdgcn_mfma_f32_32x32x16_f16(
                af[ks][s], bf[ks][nt], acc[s][nt], 0, 0, 0);
      if (j + 1 < NT) {
        if (t == 8) {
          __syncthreads();             // all waves done reading As for this cc
          if (doA) { stA(); ldA(cc + 2 < NC ? cc + 2 : NC - 1); }
        }
        __syncthreads();
      }
    }
  }

  // epilogue: bias + relu, store [HW][256] fp16
  // C/D: col = lane&31, row = (r&3) + 8*(r>>2) + 4*(lane>>5)
#pragma unroll
  for (int s = 0; s < 2; ++s)
#pragma unroll
    for (int nt = 0; nt < 4; ++nt) {
      int n = nwave * 128 + nt * 32 + l31;
      float bn = bias[n];
#pragma unroll
      for (int r = 0; r < 16; ++r) {
        int mrow = (r & 3) + 8 * (r >> 2) + 4 * khalf;
        int y = y0 + mwave * 4 + s * 2 + (mrow >> 4);
        int x = x0 + (mrow & 15);
        float v = fmaxf(acc[s][nt][r] + bn, 0.f);
        actout[((size_t)(y * 256 + x) << 8) + n] = (_Float16)v;
      }
    }
}

// ---------------------------------------------------------------------------
// Head (one batch): logit_k(px) = wmu2_k . act2[px] + lgb[k]; softmax over
// 16; dot with label. One pixel per thread, all fp32 VALU.
// ---------------------------------------------------------------------------
__global__ __launch_bounds__(256) void k_head(
    const _Float16* __restrict__ act2, const float* __restrict__ wmu2,
    const float* __restrict__ lgb, const float* __restrict__ label,
    float* __restrict__ out) {
  int px = blockIdx.x * 256 + threadIdx.x;
  const half8* ap = (const half8*)(act2 + ((size_t)px << 8));
  float cr[16];
#pragma unroll
  for (int k = 0; k < 16; ++k) cr[k] = lgb[k];
#pragma unroll 2
  for (int cc = 0; cc < 32; ++cc) {
    half8 h = ap[cc];
    float a0 = (float)h[0], a1 = (float)h[1], a2 = (float)h[2],
          a3 = (float)h[3], a4 = (float)h[4], a5 = (float)h[5],
          a6 = (float)h[6], a7 = (float)h[7];
#pragma unroll
    for (int k = 0; k < 16; ++k) {
      const float* w = wmu2 + (k << 8) + (cc << 3);
      float c0 = cr[k];
      c0 = fmaf(a0, w[0], c0);
      c0 = fmaf(a1, w[1], c0);
      c0 = fmaf(a2, w[2], c0);
      c0 = fmaf(a3, w[3], c0);
      c0 = fmaf(a4, w[4], c0);
      c0 = fmaf(a5, w[5], c0);
      c0 = fmaf(a6, w[6], c0);
      c0 = fmaf(a7, w[7], c0);
      cr[k] = c0;
    }
  }
  float mx = cr[0];
#pragma unroll
  for (int k = 1; k < 16; ++k) mx = fmaxf(mx, cr[k]);
  float num = 0.f, den = 0.f;
#pragma unroll
  for (int k = 0; k < 16; ++k) {
    float e = __expf(cr[k] - mx);
    num = fmaf(e, label[k], num);
    den += e;
  }
  out[px] = num / den;
}

// ---------------------------------------------------------------------------
extern "C" void kernel_launch(void* const* d_in, const int* in_sizes, int n_in,
                              void* d_out, int out_size, void* d_ws, size_t ws_size,
                              hipStream_t stream) {
  const float* x  = (const float*)d_in[0];
  const float* w1 = (const float*)d_in[1];
  const float* b1 = (const float*)d_in[2];
  const float* w2 = (const float*)d_in[3];
  const float* b2 = (const float*)d_in[4];
  const float* w3 = (const float*)d_in[5];
  const float* b3 = (const float*)d_in[6];
  const float* mu = (const float*)d_in[7];
  const float* label = (const float*)d_in[8];
  float* out = (float*)d_out;

  char* ws = (char*)d_ws;
  _Float16* w1r  = (_Float16*)(ws + OFF_W1R);
  _Float16* w2r  = (_Float16*)(ws + OFF_W2R);
  float*    wmu2 = (float*)   (ws + OFF_WMU);
  float*    lgb  = (float*)   (ws + OFF_LGB);
  _Float16* buf1 = (_Float16*)(ws + OFF_BUF1);   // act1 (current batch)
  _Float16* buf2 = (_Float16*)(ws + OFF_BUF2);   // act0 then act2

  k_prep<<<2897, 256, 0, stream>>>(w1, w2, w3, b3, mu, w1r, w2r, wmu2, lgb);
  for (int b = 0; b < BB; ++b) {
    k_t0<<<1024, 256, 0, stream>>>(x + (size_t)b * CIN * 65536, buf2);
    k_conv<64><<<512, 256, 0, stream>>>(buf2, w1r, b1, buf1);
    k_conv<256><<<512, 256, 0, stream>>>(buf1, w2r, b2, buf2);
    k_head<<<256, 256, 0, stream>>>(buf2, wmu2, lgb, label,
                                    out + (size_t)b * 65536);
  }
}

// Round 6
// 789.856 us; speedup vs baseline: 1.7261x; 1.7261x over previous
//
#include <hip/hip_runtime.h>

// Problem constants
#define BB   4
#define CIN  64
#define HH   256
#define WW   256
#define QQ   256
#define KK   16

typedef _Float16 half8 __attribute__((ext_vector_type(8)));
typedef float   f32x16 __attribute__((ext_vector_type(16)));
typedef unsigned int u32;

// ---- workspace layout (bytes) ----
// w1r: fp16, swizzled DMA image, 18 blks x 16 KB = 294912
// w2r: fp16, swizzled DMA image, 72 blks x 16 KB = 1179648
// wmu2/lgb: folded head
// per-batch mode: buf1 32MB @ OFF_BUF1, buf2 32MB @ OFF_BUF2 (total 65.5 MiB)
// fused mode (ws_size >= 303595776): act0 32MB @ OFF_BUF1, act1 128MB, act2 128MB
#define OFF_W1R   0ull
#define OFF_W2R   294912ull
#define OFF_WMU   1474560ull
#define OFF_LGB   1490944ull
#define OFF_BUF1  1605888ull
#define OFF_BUF2  35160320ull
#define OFF_A1F   35160320ull
#define OFF_A2F   169378048ull
#define WS_FUSED  303595776ull

__device__ __forceinline__ void dma16(const void* g, void* l) {
  __builtin_amdgcn_global_load_lds(
      (const __attribute__((address_space(1))) u32*)g,
      (__attribute__((address_space(3))) u32*)l, 16, 0, 0);
}

// ---------------------------------------------------------------------------
// Prep: build swizzled DMA images of conv weights.
// Block (cc,tt) = 16 KB: 256 rows(n) x 32 ch; quarter q (8 ch) of row n is
// stored at slot q^(n&3). Fold head: wmu2[k][c] = 2*sum_o mu[k][o]*w3[o][c];
// lgb[k] = 2*mu_k.b3 - |mu_k|^2.
// ---------------------------------------------------------------------------
__global__ __launch_bounds__(256) void k_prep(
    const float* __restrict__ w1, const float* __restrict__ w2,
    const float* __restrict__ w3, const float* __restrict__ b3,
    const float* __restrict__ mu,
    _Float16* __restrict__ w1r, _Float16* __restrict__ w2r,
    float* __restrict__ wmu2, float* __restrict__ lgb) {
  int idx = blockIdx.x * 256 + threadIdx.x;
  if (idx < 147456) {                       // w1r (CI=64): 18 blocks
    int blk = idx >> 13;
    int cc = blk / 9, tt = blk - cc * 9;
    int rem = idx & 8191;
    int n = rem >> 5, r = rem & 31;
    int q = (r >> 3) ^ (n & 3), e = r & 7;
    int c = cc * 32 + q * 8 + e;
    w1r[idx] = (_Float16)w1[(n * 64 + c) * 9 + tt];
  } else if (idx < 737280) {                // w2r (CI=256): 72 blocks
    int d = idx - 147456;
    int blk = d >> 13;
    int cc = blk / 9, tt = blk - cc * 9;
    int rem = d & 8191;
    int n = rem >> 5, r = rem & 31;
    int q = (r >> 3) ^ (n & 3), e = r & 7;
    int c = cc * 32 + q * 8 + e;
    w2r[d] = (_Float16)w2[(n * 256 + c) * 9 + tt];
  } else if (idx < 741376) {                // wmu2: [16 k][256 c]
    int j = idx - 737280;
    int k = j >> 8, c = j & 255;
    float s = 0.f;
    for (int o = 0; o < 256; ++o) s = fmaf(mu[k * 256 + o], w3[o * 256 + c], s);
    wmu2[j] = 2.f * s;
  } else if (idx < 741392) {                // lgb: [16]
    int k = idx - 741376;
    float s1 = 0.f, s2 = 0.f;
    for (int o = 0; o < 256; ++o) {
      float m = mu[k * 256 + o];
      s1 = fmaf(m, b3[o], s1);
      s2 = fmaf(m, m, s2);
    }
    lgb[k] = 2.f * s1 - s2;
  }
}

// ---------------------------------------------------------------------------
// T0: x NCHW fp32 -> act0 [b][HW][64] fp16 (LDS transpose). b = blockIdx>>10.
// ---------------------------------------------------------------------------
__global__ __launch_bounds__(256) void k_t0(const float* __restrict__ x,
                                            _Float16* __restrict__ act0) {
  __shared__ float tile[64][65];
  int blk = blockIdx.x;
  int b = blk >> 10;
  int p0 = (blk & 1023) << 6;
  int t = threadIdx.x;
  {
    int p = t & 63, c0 = t >> 6;
    const float* xb = x + (size_t)b * (CIN * 65536) + p0 + p;
#pragma unroll
    for (int i = 0; i < 16; ++i) {
      int c = c0 + (i << 2);
      tile[c][p] = xb[(size_t)c * 65536];
    }
  }
  __syncthreads();
  {
    int c = t & 63, p1 = t >> 6;
    _Float16* o = act0 + ((size_t)b * 65536 + p0) * CIN + c;
#pragma unroll
    for (int i = 0; i < 16; ++i) {
      int p = p1 + (i << 2);
      o[(size_t)p * CIN] = (_Float16)tile[c][p];
    }
  }
}

// ---------------------------------------------------------------------------
// Conv 3x3 (replicate pad) + bias + ReLU, implicit GEMM, 32x32x16 fp16 MFMA.
// Block: 256 thr (4 waves, 2x2), tile 128 px (16w x 8h) x 256 ch (full N).
// All staging via global_load_lds DMA (no VGPR round-trip): As/Bs double-
// buffered, DMA for tap j+1 issued before tap j's MFMAs, 1 barrier/tap.
// Bank conflicts killed by source-side XOR swizzle (slot = q^(row&3)).
// grid = 512*NB; b = blockIdx>>9.
// ---------------------------------------------------------------------------
template <int CI>
__global__ __launch_bounds__(256, 2) void k_conv(
    const _Float16* __restrict__ actin, const char* __restrict__ wr,
    const float* __restrict__ bias, _Float16* __restrict__ actout) {
  constexpr int NC = CI / 32;
  constexpr int NT = 9 * NC;
  __shared__ __align__(16) char As[2][12288];   // 192 px x 64 B (180 used)
  __shared__ __align__(16) char Bs[2][16384];   // 256 n x 64 B

  int tid = threadIdx.x;
  int b = blockIdx.x >> 9;
  int tile = blockIdx.x & 511;
  int txi = tile & 15, tyi = tile >> 4;
  int x0 = txi << 4, y0 = tyi << 3;
  int lane = tid & 63, wave = tid >> 6;
  int mwave = wave >> 1, nwave = wave & 1;
  int l31 = lane & 31, khalf = lane >> 5;

  f32x16 acc[2][4];
#pragma unroll
  for (int s = 0; s < 2; ++s)
#pragma unroll
    for (int nt = 0; nt < 4; ++nt)
#pragma unroll
      for (int r = 0; r < 16; ++r) acc[s][nt][r] = 0.f;

  // ---- A DMA setup: 3 wave-instrs, 16 px each (lane i -> px base+i/4,
  // slot i&3). Source quarter permuted so LDS slot s holds quarter s^(px&3).
  const char* aG[3];
  int aL[3];
#pragma unroll
  for (int i = 0; i < 3; ++i) {
    int px = (wave * 3 + i) * 16 + (lane >> 2);
    int s = lane & 3;
    int pxc = min(px, 179);
    int hy = pxc / 18, hx = pxc - hy * 18;
    int y = min(max(y0 - 1 + hy, 0), 255);
    int x = min(max(x0 - 1 + hx, 0), 255);
    int q = s ^ (pxc & 3);
    aG[i] = (const char*)actin +
            (((size_t)(b * 65536 + y * 256 + x)) * CI + q * 8) * 2;
    aL[i] = (wave * 3 + i) * 1024;   // wave-uniform LDS base
  }
  // ---- B DMA: pure linear copy (swizzle baked into wr by k_prep) ----
  const char* bG = wr + wave * 4096 + lane * 16;
  int bL = wave * 4096;

  // Prologue: stage A(0)->As[0], B(0)->Bs[0]
#pragma unroll
  for (int i = 0; i < 3; ++i) dma16(aG[i], &As[0][aL[i]]);
#pragma unroll
  for (int i = 0; i < 4; ++i) dma16(bG + i * 1024, &Bs[0][bL + i * 1024]);
  __syncthreads();

  for (int cc = 0; cc < NC; ++cc) {
#pragma unroll
    for (int t = 0; t < 9; ++t) {
      int j = cc * 9 + t;
      // issue DMA for tap j+1 (latency covered by this tap's MFMAs)
      if (j + 1 < NT) {
        const char* bsrc = bG + (size_t)(j + 1) * 16384;
        char* bdst = &Bs[(j + 1) & 1][bL];
#pragma unroll
        for (int i = 0; i < 4; ++i) dma16(bsrc + i * 1024, bdst + i * 1024);
        if (t == 8) {
#pragma unroll
          for (int i = 0; i < 3; ++i)
            dma16(aG[i] + (cc + 1) * 64, &As[(cc + 1) & 1][aL[i]]);
        }
      }
      // fragment reads (swizzled addressing)
      int dy = t / 3, dx = t - dy * 3;
      const char* Ab = As[cc & 1];
      const char* Bb = Bs[j & 1];
      half8 af[2][2], bf[2][4];
#pragma unroll
      for (int s = 0; s < 2; ++s) {
        int px = (mwave * 4 + s * 2 + (l31 >> 4) + dy) * 18 + (l31 & 15) + dx;
        int sw = (px & 3) << 4;
#pragma unroll
        for (int ks = 0; ks < 2; ++ks) {
          int q = (ks * 2 + khalf) << 4;
          af[ks][s] = *(const half8*)(Ab + px * 64 + (q ^ sw));
        }
      }
#pragma unroll
      for (int nt = 0; nt < 4; ++nt) {
        int n = nwave * 128 + nt * 32 + l31;
        int sw = (n & 3) << 4;
#pragma unroll
        for (int ks = 0; ks < 2; ++ks) {
          int q = (ks * 2 + khalf) << 4;
          bf[ks][nt] = *(const half8*)(Bb + n * 64 + (q ^ sw));
        }
      }
#pragma unroll
      for (int ks = 0; ks < 2; ++ks)
#pragma unroll
        for (int s = 0; s < 2; ++s)
#pragma unroll
          for (int nt = 0; nt < 4; ++nt)
            acc[s][nt] = __builtin_amdgcn_mfma_f32_32x32x16_f16(
                af[ks][s], bf[ks][nt], acc[s][nt], 0, 0, 0);
      __syncthreads();   // drains DMA queue; next tap's buffers ready
    }
  }

  // epilogue: bias + relu, store [b][HW][256] fp16
  // C/D (verified r5): col = lane&31, row = (r&3) + 8*(r>>2) + 4*(lane>>5)
#pragma unroll
  for (int s = 0; s < 2; ++s)
#pragma unroll
    for (int nt = 0; nt < 4; ++nt) {
      int n = nwave * 128 + nt * 32 + l31;
      float bn = bias[n];
#pragma unroll
      for (int r = 0; r < 16; ++r) {
        int mrow = (r & 3) + 8 * (r >> 2) + 4 * khalf;
        int y = y0 + mwave * 4 + s * 2 + (mrow >> 4);
        int x = x0 + (mrow & 15);
        float v = fmaxf(acc[s][nt][r] + bn, 0.f);
        actout[(((size_t)(b * 65536 + y * 256 + x)) << 8) + n] = (_Float16)v;
      }
    }
}

// ---------------------------------------------------------------------------
// Head: logit_k(px) = wmu2_k . act2[px] + lgb[k]; softmax over 16; dot with
// label. One pixel per thread, all fp32 VALU.
// ---------------------------------------------------------------------------
__global__ __launch_bounds__(256) void k_head(
    const _Float16* __restrict__ act2, const float* __restrict__ wmu2,
    const float* __restrict__ lgb, const float* __restrict__ label,
    float* __restrict__ out) {
  int px = blockIdx.x * 256 + threadIdx.x;
  const half8* ap = (const half8*)(act2 + ((size_t)px << 8));
  float cr[16];
#pragma unroll
  for (int k = 0; k < 16; ++k) cr[k] = lgb[k];
#pragma unroll 2
  for (int cc = 0; cc < 32; ++cc) {
    half8 h = ap[cc];
    float a0 = (float)h[0], a1 = (float)h[1], a2 = (float)h[2],
          a3 = (float)h[3], a4 = (float)h[4], a5 = (float)h[5],
          a6 = (float)h[6], a7 = (float)h[7];
#pragma unroll
    for (int k = 0; k < 16; ++k) {
      const float* w = wmu2 + (k << 8) + (cc << 3);
      float c0 = cr[k];
      c0 = fmaf(a0, w[0], c0);
      c0 = fmaf(a1, w[1], c0);
      c0 = fmaf(a2, w[2], c0);
      c0 = fmaf(a3, w[3], c0);
      c0 = fmaf(a4, w[4], c0);
      c0 = fmaf(a5, w[5], c0);
      c0 = fmaf(a6, w[6], c0);
      c0 = fmaf(a7, w[7], c0);
      cr[k] = c0;
    }
  }
  float mx = cr[0];
#pragma unroll
  for (int k = 1; k < 16; ++k) mx = fmaxf(mx, cr[k]);
  float num = 0.f, den = 0.f;
#pragma unroll
  for (int k = 0; k < 16; ++k) {
    float e = __expf(cr[k] - mx);
    num = fmaf(e, label[k], num);
    den += e;
  }
  out[px] = num / den;
}

// ---------------------------------------------------------------------------
extern "C" void kernel_launch(void* const* d_in, const int* in_sizes, int n_in,
                              void* d_out, int out_size, void* d_ws, size_t ws_size,
                              hipStream_t stream) {
  const float* x  = (const float*)d_in[0];
  const float* w1 = (const float*)d_in[1];
  const float* b1 = (const float*)d_in[2];
  const float* w2 = (const float*)d_in[3];
  const float* b2 = (const float*)d_in[4];
  const float* w3 = (const float*)d_in[5];
  const float* b3 = (const float*)d_in[6];
  const float* mu = (const float*)d_in[7];
  const float* label = (const float*)d_in[8];
  float* out = (float*)d_out;

  char* ws = (char*)d_ws;
  _Float16* w1r  = (_Float16*)(ws + OFF_W1R);
  _Float16* w2r  = (_Float16*)(ws + OFF_W2R);
  float*    wmu2 = (float*)   (ws + OFF_WMU);
  float*    lgb  = (float*)   (ws + OFF_LGB);

  k_prep<<<2897, 256, 0, stream>>>(w1, w2, w3, b3, mu, w1r, w2r, wmu2, lgb);

  if (ws_size >= WS_FUSED) {
    // fused: one dispatch per stage, all 4 batches
    _Float16* act0 = (_Float16*)(ws + OFF_BUF1);   // [4][HW][64]
    _Float16* act1 = (_Float16*)(ws + OFF_A1F);    // [4][HW][256]
    _Float16* act2 = (_Float16*)(ws + OFF_A2F);    // [4][HW][256]
    k_t0<<<4096, 256, 0, stream>>>(x, act0);
    k_conv<64><<<2048, 256, 0, stream>>>(act0, (const char*)w1r, b1, act1);
    k_conv<256><<<2048, 256, 0, stream>>>(act1, (const char*)w2r, b2, act2);
    k_head<<<1024, 256, 0, stream>>>(act2, wmu2, lgb, label, out);
  } else {
    // per-batch: 64 MB of activation buffers
    _Float16* buf1 = (_Float16*)(ws + OFF_BUF1);
    _Float16* buf2 = (_Float16*)(ws + OFF_BUF2);
    for (int b = 0; b < BB; ++b) {
      k_t0<<<1024, 256, 0, stream>>>(x + (size_t)b * CIN * 65536, buf2);
      k_conv<64><<<512, 256, 0, stream>>>(buf2, (const char*)w1r, b1, buf1);
      k_conv<256><<<512, 256, 0, stream>>>(buf1, (const char*)w2r, b2, buf2);
      k_head<<<256, 256, 0, stream>>>(buf2, wmu2, lgb, label,
                                      out + (size_t)b * 65536);
    }
  }
}

// Round 7
// 788.862 us; speedup vs baseline: 1.7283x; 1.0013x over previous
//
#include <hip/hip_runtime.h>

// Problem constants
#define BB   4
#define CIN  64
#define HH   256
#define WW   256
#define QQ   256
#define KK   16

typedef _Float16 half8 __attribute__((ext_vector_type(8)));
typedef float   f32x16 __attribute__((ext_vector_type(16)));
typedef unsigned int u32;

// ---- workspace layout (bytes) ----
#define OFF_W1R   0ull
#define OFF_W2R   294912ull
#define OFF_WMU   1474560ull
#define OFF_LGB   1490944ull
#define OFF_BUF1  1605888ull
#define OFF_BUF2  35160320ull
#define OFF_A1F   35160320ull
#define OFF_A2F   169378048ull
#define WS_FUSED  303595776ull

__device__ __forceinline__ void dma16(const void* g, void* l) {
  __builtin_amdgcn_global_load_lds(
      (const __attribute__((address_space(1))) u32*)g,
      (__attribute__((address_space(3))) u32*)l, 16, 0, 0);
}

// ---------------------------------------------------------------------------
// Prep: build swizzled DMA images of conv weights.
// Block (cc,tt) = 16 KB: 256 rows(n) x 32 ch; 16B-quarter q of row n stored
// at slot q^((n>>1)&3)  [bank-group g=(4n+s)%8 then covers all 8 groups over
// any 8 consecutive rows -> conflict-free b128 fragment reads].
// Fold head: wmu2[k][c] = 2*sum_o mu[k][o]*w3[o][c]; lgb[k]=2*mu_k.b3-|mu_k|^2.
// ---------------------------------------------------------------------------
__global__ __launch_bounds__(256) void k_prep(
    const float* __restrict__ w1, const float* __restrict__ w2,
    const float* __restrict__ w3, const float* __restrict__ b3,
    const float* __restrict__ mu,
    _Float16* __restrict__ w1r, _Float16* __restrict__ w2r,
    float* __restrict__ wmu2, float* __restrict__ lgb) {
  int idx = blockIdx.x * 256 + threadIdx.x;
  if (idx < 147456) {                       // w1r (CI=64): 18 blocks
    int blk = idx >> 13;
    int cc = blk / 9, tt = blk - cc * 9;
    int rem = idx & 8191;
    int n = rem >> 5, r = rem & 31;
    int q = (r >> 3) ^ ((n >> 1) & 3), e = r & 7;
    int c = cc * 32 + q * 8 + e;
    w1r[idx] = (_Float16)w1[(n * 64 + c) * 9 + tt];
  } else if (idx < 737280) {                // w2r (CI=256): 72 blocks
    int d = idx - 147456;
    int blk = d >> 13;
    int cc = blk / 9, tt = blk - cc * 9;
    int rem = d & 8191;
    int n = rem >> 5, r = rem & 31;
    int q = (r >> 3) ^ ((n >> 1) & 3), e = r & 7;
    int c = cc * 32 + q * 8 + e;
    w2r[d] = (_Float16)w2[(n * 256 + c) * 9 + tt];
  } else if (idx < 741376) {                // wmu2: [16 k][256 c]
    int j = idx - 737280;
    int k = j >> 8, c = j & 255;
    float s = 0.f;
    for (int o = 0; o < 256; ++o) s = fmaf(mu[k * 256 + o], w3[o * 256 + c], s);
    wmu2[j] = 2.f * s;
  } else if (idx < 741392) {                // lgb: [16]
    int k = idx - 741376;
    float s1 = 0.f, s2 = 0.f;
    for (int o = 0; o < 256; ++o) {
      float m = mu[k * 256 + o];
      s1 = fmaf(m, b3[o], s1);
      s2 = fmaf(m, m, s2);
    }
    lgb[k] = 2.f * s1 - s2;
  }
}

// ---------------------------------------------------------------------------
// T0: x NCHW fp32 -> act0 [b][HW][64] fp16 (LDS transpose). b = blockIdx>>10.
// ---------------------------------------------------------------------------
__global__ __launch_bounds__(256) void k_t0(const float* __restrict__ x,
                                            _Float16* __restrict__ act0) {
  __shared__ float tile[64][65];
  int blk = blockIdx.x;
  int b = blk >> 10;
  int p0 = (blk & 1023) << 6;
  int t = threadIdx.x;
  {
    int p = t & 63, c0 = t >> 6;
    const float* xb = x + (size_t)b * (CIN * 65536) + p0 + p;
#pragma unroll
    for (int i = 0; i < 16; ++i) {
      int c = c0 + (i << 2);
      tile[c][p] = xb[(size_t)c * 65536];
    }
  }
  __syncthreads();
  {
    int c = t & 63, p1 = t >> 6;
    _Float16* o = act0 + ((size_t)b * 65536 + p0) * CIN + c;
#pragma unroll
    for (int i = 0; i < 16; ++i) {
      int p = p1 + (i << 2);
      o[(size_t)p * CIN] = (_Float16)tile[c][p];
    }
  }
}

// ---------------------------------------------------------------------------
// Conv 3x3 (replicate pad) + bias + ReLU, implicit GEMM, 32x32x16 fp16 MFMA.
// Block: 256 thr (4 waves, 2x2), tile 128 px (16w x 8h) x 256 ch (full N).
// All staging via global_load_lds DMA, As/Bs double-buffered, DMA for tap
// j+1 issued before tap j's MFMAs, 1 barrier/tap.
// Bank conflicts killed by XOR swizzle slot = q ^ ((row>>1)&3).
// grid = 512*NB; b = blockIdx>>9.
// ---------------------------------------------------------------------------
template <int CI>
__global__ __launch_bounds__(256, 2) void k_conv(
    const _Float16* __restrict__ actin, const char* __restrict__ wr,
    const float* __restrict__ bias, _Float16* __restrict__ actout) {
  constexpr int NC = CI / 32;
  constexpr int NT = 9 * NC;
  __shared__ __align__(16) char As[2][12288];   // 192 px x 64 B (180 used)
  __shared__ __align__(16) char Bs[2][16384];   // 256 n x 64 B

  int tid = threadIdx.x;
  int b = blockIdx.x >> 9;
  int tile = blockIdx.x & 511;
  int txi = tile & 15, tyi = tile >> 4;
  int x0 = txi << 4, y0 = tyi << 3;
  int lane = tid & 63, wave = tid >> 6;
  int mwave = wave >> 1, nwave = wave & 1;
  int l31 = lane & 31, khalf = lane >> 5;

  f32x16 acc[2][4];
#pragma unroll
  for (int s = 0; s < 2; ++s)
#pragma unroll
    for (int nt = 0; nt < 4; ++nt)
#pragma unroll
      for (int r = 0; r < 16; ++r) acc[s][nt][r] = 0.f;

  // ---- A DMA setup: 3 wave-instrs, 16 px each (lane i -> px base+i/4,
  // slot i&3). Source quarter q = s ^ ((px>>1)&3) so LDS slot s holds the
  // bank-group-spread image.
  const char* aG[3];
  int aL[3];
#pragma unroll
  for (int i = 0; i < 3; ++i) {
    int px = (wave * 3 + i) * 16 + (lane >> 2);
    int s = lane & 3;
    int pxc = min(px, 179);
    int hy = pxc / 18, hx = pxc - hy * 18;
    int y = min(max(y0 - 1 + hy, 0), 255);
    int x = min(max(x0 - 1 + hx, 0), 255);
    int q = s ^ ((pxc >> 1) & 3);
    aG[i] = (const char*)actin +
            (((size_t)(b * 65536 + y * 256 + x)) * CI + q * 8) * 2;
    aL[i] = (wave * 3 + i) * 1024;   // wave-uniform LDS base
  }
  // ---- B DMA: pure linear copy (swizzle baked into wr by k_prep) ----
  const char* bG = wr + wave * 4096 + lane * 16;
  int bL = wave * 4096;

  // Prologue: stage A(0)->As[0], B(0)->Bs[0]
#pragma unroll
  for (int i = 0; i < 3; ++i) dma16(aG[i], &As[0][aL[i]]);
#pragma unroll
  for (int i = 0; i < 4; ++i) dma16(bG + i * 1024, &Bs[0][bL + i * 1024]);
  __syncthreads();

  for (int cc = 0; cc < NC; ++cc) {
#pragma unroll
    for (int t = 0; t < 9; ++t) {
      int j = cc * 9 + t;
      // issue DMA for tap j+1 (latency covered by this tap's MFMAs)
      if (j + 1 < NT) {
        const char* bsrc = bG + (size_t)(j + 1) * 16384;
        char* bdst = &Bs[(j + 1) & 1][bL];
#pragma unroll
        for (int i = 0; i < 4; ++i) dma16(bsrc + i * 1024, bdst + i * 1024);
        if (t == 8) {
#pragma unroll
          for (int i = 0; i < 3; ++i)
            dma16(aG[i] + (cc + 1) * 64, &As[(cc + 1) & 1][aL[i]]);
        }
      }
      // fragment reads (swizzled addressing)
      int dy = t / 3, dx = t - dy * 3;
      const char* Ab = As[cc & 1];
      const char* Bb = Bs[j & 1];
      half8 af[2][2], bf[2][4];
#pragma unroll
      for (int s = 0; s < 2; ++s) {
        int px = (mwave * 4 + s * 2 + (l31 >> 4) + dy) * 18 + (l31 & 15) + dx;
        int sw = ((px >> 1) & 3) << 4;
#pragma unroll
        for (int ks = 0; ks < 2; ++ks) {
          int q = (ks * 2 + khalf) << 4;
          af[ks][s] = *(const half8*)(Ab + px * 64 + (q ^ sw));
        }
      }
#pragma unroll
      for (int nt = 0; nt < 4; ++nt) {
        int n = nwave * 128 + nt * 32 + l31;
        int sw = ((n >> 1) & 3) << 4;
#pragma unroll
        for (int ks = 0; ks < 2; ++ks) {
          int q = (ks * 2 + khalf) << 4;
          bf[ks][nt] = *(const half8*)(Bb + n * 64 + (q ^ sw));
        }
      }
#pragma unroll
      for (int ks = 0; ks < 2; ++ks)
#pragma unroll
        for (int s = 0; s < 2; ++s)
#pragma unroll
          for (int nt = 0; nt < 4; ++nt)
            acc[s][nt] = __builtin_amdgcn_mfma_f32_32x32x16_f16(
                af[ks][s], bf[ks][nt], acc[s][nt], 0, 0, 0);
      __syncthreads();   // drains DMA queue; next tap's buffers ready
    }
  }

  // epilogue: bias + relu, store [b][HW][256] fp16
  // C/D (verified r5): col = lane&31, row = (r&3) + 8*(r>>2) + 4*(lane>>5)
#pragma unroll
  for (int s = 0; s < 2; ++s)
#pragma unroll
    for (int nt = 0; nt < 4; ++nt) {
      int n = nwave * 128 + nt * 32 + l31;
      float bn = bias[n];
#pragma unroll
      for (int r = 0; r < 16; ++r) {
        int mrow = (r & 3) + 8 * (r >> 2) + 4 * khalf;
        int y = y0 + mwave * 4 + s * 2 + (mrow >> 4);
        int x = x0 + (mrow & 15);
        float v = fmaxf(acc[s][nt][r] + bn, 0.f);
        actout[(((size_t)(b * 65536 + y * 256 + x)) << 8) + n] = (_Float16)v;
      }
    }
}

// ---------------------------------------------------------------------------
// Head: logit_k(px) = wmu2_k . act2[px] + lgb[k]; softmax over 16; dot with
// label. One pixel per thread, all fp32 VALU.
// ---------------------------------------------------------------------------
__global__ __launch_bounds__(256) void k_head(
    const _Float16* __restrict__ act2, const float* __restrict__ wmu2,
    const float* __restrict__ lgb, const float* __restrict__ label,
    float* __restrict__ out) {
  int px = blockIdx.x * 256 + threadIdx.x;
  const half8* ap = (const half8*)(act2 + ((size_t)px << 8));
  float cr[16];
#pragma unroll
  for (int k = 0; k < 16; ++k) cr[k] = lgb[k];
#pragma unroll 2
  for (int cc = 0; cc < 32; ++cc) {
    half8 h = ap[cc];
    float a0 = (float)h[0], a1 = (float)h[1], a2 = (float)h[2],
          a3 = (float)h[3], a4 = (float)h[4], a5 = (float)h[5],
          a6 = (float)h[6], a7 = (float)h[7];
#pragma unroll
    for (int k = 0; k < 16; ++k) {
      const float* w = wmu2 + (k << 8) + (cc << 3);
      float c0 = cr[k];
      c0 = fmaf(a0, w[0], c0);
      c0 = fmaf(a1, w[1], c0);
      c0 = fmaf(a2, w[2], c0);
      c0 = fmaf(a3, w[3], c0);
      c0 = fmaf(a4, w[4], c0);
      c0 = fmaf(a5, w[5], c0);
      c0 = fmaf(a6, w[6], c0);
      c0 = fmaf(a7, w[7], c0);
      cr[k] = c0;
    }
  }
  float mx = cr[0];
#pragma unroll
  for (int k = 1; k < 16; ++k) mx = fmaxf(mx, cr[k]);
  float num = 0.f, den = 0.f;
#pragma unroll
  for (int k = 0; k < 16; ++k) {
    float e = __expf(cr[k] - mx);
    num = fmaf(e, label[k], num);
    den += e;
  }
  out[px] = num / den;
}

// ---------------------------------------------------------------------------
extern "C" void kernel_launch(void* const* d_in, const int* in_sizes, int n_in,
                              void* d_out, int out_size, void* d_ws, size_t ws_size,
                              hipStream_t stream) {
  const float* x  = (const float*)d_in[0];
  const float* w1 = (const float*)d_in[1];
  const float* b1 = (const float*)d_in[2];
  const float* w2 = (const float*)d_in[3];
  const float* b2 = (const float*)d_in[4];
  const float* w3 = (const float*)d_in[5];
  const float* b3 = (const float*)d_in[6];
  const float* mu = (const float*)d_in[7];
  const float* label = (const float*)d_in[8];
  float* out = (float*)d_out;

  char* ws = (char*)d_ws;
  _Float16* w1r  = (_Float16*)(ws + OFF_W1R);
  _Float16* w2r  = (_Float16*)(ws + OFF_W2R);
  float*    wmu2 = (float*)   (ws + OFF_WMU);
  float*    lgb  = (float*)   (ws + OFF_LGB);

  k_prep<<<2897, 256, 0, stream>>>(w1, w2, w3, b3, mu, w1r, w2r, wmu2, lgb);

  if (ws_size >= WS_FUSED) {
    // fused: one dispatch per stage, all 4 batches
    _Float16* act0 = (_Float16*)(ws + OFF_BUF1);   // [4][HW][64]
    _Float16* act1 = (_Float16*)(ws + OFF_A1F);    // [4][HW][256]
    _Float16* act2 = (_Float16*)(ws + OFF_A2F);    // [4][HW][256]
    k_t0<<<4096, 256, 0, stream>>>(x, act0);
    k_conv<64><<<2048, 256, 0, stream>>>(act0, (const char*)w1r, b1, act1);
    k_conv<256><<<2048, 256, 0, stream>>>(act1, (const char*)w2r, b2, act2);
    k_head<<<1024, 256, 0, stream>>>(act2, wmu2, lgb, label, out);
  } else {
    // per-batch: 64 MB of activation buffers
    _Float16* buf1 = (_Float16*)(ws + OFF_BUF1);
    _Float16* buf2 = (_Float16*)(ws + OFF_BUF2);
    for (int b = 0; b < BB; ++b) {
      k_t0<<<1024, 256, 0, stream>>>(x + (size_t)b * CIN * 65536, buf2);
      k_conv<64><<<512, 256, 0, stream>>>(buf2, (const char*)w1r, b1, buf1);
      k_conv<256><<<512, 256, 0, stream>>>(buf1, (const char*)w2r, b2, buf2);
      k_head<<<256, 256, 0, stream>>>(buf2, wmu2, lgb, label,
                                      out + (size_t)b * 65536);
    }
  }
}